// Round 6
// baseline (647.733 us; speedup 1.0000x reference)
//
#include <hip/hip_runtime.h>
#include <hip/hip_bf16.h>
#include <math.h>

// Problem constants
#define B_   4
#define N_   2048
#define DIM_ 1024
#define H_   16
#define DH_  64
#define E3_  3072   // 3*H*DH

typedef __attribute__((ext_vector_type(8))) short  s8v;   // 8 bf16 (4 VGPRs)
typedef __attribute__((ext_vector_type(4))) float  f4v;   // MFMA accumulator

__device__ __forceinline__ unsigned short f2bf(float f) {
    return __builtin_bit_cast(unsigned short, __float2bfloat16(f));
}

// async global->LDS, 16 B per lane; LDS dest = wave-uniform base + lane*16
__device__ __forceinline__ void gload_lds16(const void* g, void* l) {
    __builtin_amdgcn_global_load_lds(
        (const __attribute__((address_space(1))) unsigned int*)(uintptr_t)g,
        (__attribute__((address_space(3))) unsigned int*)(uintptr_t)l,
        16, 0, 0);
}

// ---------------------------------------------------------------------------
// fp32 -> bf16 convert
// ---------------------------------------------------------------------------
__global__ __launch_bounds__(256) void cvt_bf16(
    const float* __restrict__ in, unsigned short* __restrict__ out, int n)
{
    const int i = (blockIdx.x * 256 + threadIdx.x) * 4;
    if (i < n) {
        float4 v = *(const float4*)(in + i);
        *(ushort4*)(out + i) =
            make_ushort4(f2bf(v.x), f2bf(v.y), f2bf(v.z), f2bf(v.w));
    }
}

// ---------------------------------------------------------------------------
// bf16 MFMA GEMM, m97 structure: C[M,Nc] = A[M,K] @ Bw[Nc,K]^T
// 128x128 tile, BK=32, 256 thr = 4 waves (2x2), each wave 64x64 via 4x4
// 16x16x32 MFMAs. global_load_lds width 16, no LDS padding (required).
// MODE 0: out = bf16 qkv; Q-third (cols < 1024) pre-scaled by
//         0.125*log2(e) so attention can exp2() raw scores; V-third
//         (cols >= 2048) redirected to vT[b,h,d,n] (pre-transposed).
// MODE 1: out = fp32 + bias.
// ---------------------------------------------------------------------------
template<int MODE>
__global__ __launch_bounds__(256) void gemm_mfma(
    const unsigned short* __restrict__ A,
    const unsigned short* __restrict__ Bw,
    const float* __restrict__ bias,
    unsigned short* __restrict__ Cb,   // MODE 0: qkv bf16 [M][Nc]
    unsigned short* __restrict__ Vt,   // MODE 0: [B*H][64][2048]
    float* __restrict__ Cf,            // MODE 1: fp32 [M][Nc]
    int M, int Nc, int K)
{
    __shared__ unsigned short As[128 * 32];
    __shared__ unsigned short Bs[128 * 32];

    const int tid  = threadIdx.x;
    const int w    = tid >> 6;
    const int lane = tid & 63;
    const int quad = lane >> 4;
    const int l15  = lane & 15;
    const int wm   = w & 1, wn = w >> 1;
    const int m0   = blockIdx.y * 128, n0 = blockIdx.x * 128;

    const int srow = lane >> 2;        // 0..15
    const int sch  = (lane & 3) * 8;   // k element offset 0,8,16,24

    f4v acc[4][4];
    #pragma unroll
    for (int i = 0; i < 4; i++)
        #pragma unroll
        for (int j = 0; j < 4; j++) acc[i][j] = (f4v){0.f, 0.f, 0.f, 0.f};

    for (int k0 = 0; k0 < K; k0 += 32) {
        __syncthreads();   // fragment reads of prev iter complete
        #pragma unroll
        for (int i = 0; i < 2; i++) {
            const int rbase = w * 32 + i * 16;   // 16 rows per instruction
            gload_lds16(A  + (size_t)(m0 + rbase + srow) * K + k0 + sch,
                        &As[rbase * 32]);
            gload_lds16(Bw + (size_t)(n0 + rbase + srow) * K + k0 + sch,
                        &Bs[rbase * 32]);
        }
        __syncthreads();   // drains vmcnt -> LDS visible

        s8v af[4], bf[4];
        #pragma unroll
        for (int i = 0; i < 4; i++) {
            af[i] = *(const s8v*)&As[(wm * 64 + i * 16 + l15) * 32 + quad * 8];
            bf[i] = *(const s8v*)&Bs[(wn * 64 + i * 16 + l15) * 32 + quad * 8];
        }
        #pragma unroll
        for (int ms = 0; ms < 4; ms++)
            #pragma unroll
            for (int ns = 0; ns < 4; ns++)
                acc[ms][ns] = __builtin_amdgcn_mfma_f32_16x16x32_bf16(
                    af[ms], bf[ns], acc[ms][ns], 0, 0, 0);
    }

    // epilogue: C/D layout col = l15, row = quad*4 + r
    if (MODE == 0) {
        #pragma unroll
        for (int ns = 0; ns < 4; ns++) {
            const int colb = n0 + wn * 64 + ns * 16;   // wave-uniform
            if (colb < 2048) {
                // fold softmax scale*log2(e) into Q columns
                const float mul = (colb < 1024) ? 0.18033688011112042f : 1.0f;
                #pragma unroll
                for (int ms = 0; ms < 4; ms++)
                    #pragma unroll
                    for (int r = 0; r < 4; r++) {
                        const int row = m0 + wm * 64 + ms * 16 + quad * 4 + r;
                        Cb[(size_t)row * Nc + colb + l15] = f2bf(acc[ms][ns][r] * mul);
                    }
            } else {
                const int e = colb + l15 - 2048;
                const int h = e >> 6, d = e & 63;
                #pragma unroll
                for (int ms = 0; ms < 4; ms++)
                    #pragma unroll
                    for (int r = 0; r < 4; r++) {
                        const int row = m0 + wm * 64 + ms * 16 + quad * 4 + r;
                        const int b = row >> 11, n = row & 2047;
                        Vt[(((size_t)b * 16 + h) * 64 + d) * 2048 + n] =
                            f2bf(acc[ms][ns][r]);
                    }
            }
        }
    } else {
        #pragma unroll
        for (int ns = 0; ns < 4; ns++) {
            const float bz = bias[n0 + wn * 64 + ns * 16 + l15];
            #pragma unroll
            for (int ms = 0; ms < 4; ms++)
                #pragma unroll
                for (int r = 0; r < 4; r++) {
                    const int row = m0 + wm * 64 + ms * 16 + quad * 4 + r;
                    Cf[(size_t)row * Nc + n0 + wn * 64 + ns * 16 + l15] =
                        acc[ms][ns][r] + bz;
                }
        }
    }
}

// ---------------------------------------------------------------------------
// MFMA flash attention, max-free softmax, BARRIER-FREE:
// K/V/Q fragments loaded directly global->VGPR (per-lane 16 B pattern —
// the B-fragment layout [n=l15][k=quad*8+j] is 16 contiguous bytes in
// K rows / vT rows). Only P round-trips through LDS (wave-private rows,
// ordered by lgkmcnt; no __syncthreads in the whole kernel).
// qkv bf16 [m][3072] (Q pre-scaled by 0.125*log2e); vT[b*16+h][d][n] bf16.
// Block = 4 waves, 64 q-rows of one (b,h).
// ---------------------------------------------------------------------------
__global__ __launch_bounds__(256) void attn_mfma(
    const unsigned short* __restrict__ qkv,
    const unsigned short* __restrict__ vT,
    unsigned short* __restrict__ ao)
{
    __shared__ __align__(16) unsigned short Ps[64][72];

    const int tid  = threadIdx.x;
    const int w    = tid >> 6;
    const int lane = tid & 63;
    const int quad = lane >> 4;
    const int l15  = lane & 15;

    const int bh = blockIdx.y;
    const int b  = bh >> 4;
    const int h  = bh & 15;
    const int q0 = blockIdx.x * 64;

    const unsigned short* qp  = qkv + (size_t)b * N_ * E3_ + (size_t)h * DH_;
    const unsigned short* kp  = qp + 1024;
    const unsigned short* vtp = vT + (size_t)bh * 64 * 2048;

    // Q A-fragments straight from global: A[m=l15][k=quad*8+j], rows q0+w*16+l15
    const unsigned short* qrow = qp + (size_t)(q0 + w * 16 + l15) * E3_;
    const s8v aq0 = *(const s8v*)(qrow + quad * 8);
    const s8v aq1 = *(const s8v*)(qrow + 32 + quad * 8);

    // ones B-fragment (bf16 1.0 = 0x3F80) for the row-sum MFMA
    s8v ones;
    #pragma unroll
    for (int i = 0; i < 8; i++) ones[i] = (short)0x3F80;

    f4v o_acc[4];
    #pragma unroll
    for (int nt = 0; nt < 4; nt++) o_acc[nt] = (f4v){0.f, 0.f, 0.f, 0.f};
    f4v lacc = (f4v){0.f, 0.f, 0.f, 0.f};

    // per-lane base pointers for the fragment gathers
    // K frag (nt,ks): kp[(k0 + nt*16 + l15)*E3 + ks*32 + quad*8]
    // V frag (nt,ks): vtp[(nt*16 + l15)*2048 + k0 + ks*32 + quad*8]
    const unsigned short* kbase = kp + (size_t)l15 * E3_ + quad * 8;
    const unsigned short* vbase = vtp + (size_t)l15 * 2048 + quad * 8;

    for (int kt = 0; kt < N_ / 64; kt++) {
        const int k0 = kt * 64;

        // issue all 16 fragment loads up front (VMEM, no LDS)
        s8v bk[4][2], bv[4][2];
        #pragma unroll
        for (int nt = 0; nt < 4; nt++)
            #pragma unroll
            for (int ks = 0; ks < 2; ks++) {
                bk[nt][ks] = *(const s8v*)(kbase + (size_t)(k0 + nt * 16) * E3_ + ks * 32);
                bv[nt][ks] = *(const s8v*)(vbase + (size_t)(nt * 16) * 2048 + k0 + ks * 32);
            }

        // S = Qscaled K^T  (log2 domain)
        f4v s[4];
        #pragma unroll
        for (int nt = 0; nt < 4; nt++) {
            s[nt] = (f4v){0.f, 0.f, 0.f, 0.f};
            s[nt] = __builtin_amdgcn_mfma_f32_16x16x32_bf16(aq0, bk[nt][0], s[nt], 0, 0, 0);
            s[nt] = __builtin_amdgcn_mfma_f32_16x16x32_bf16(aq1, bk[nt][1], s[nt], 0, 0, 0);
        }

        // P = exp2(S) -> LDS (own wave's rows only; wave-private, no barrier)
        #pragma unroll
        for (int nt = 0; nt < 4; nt++)
            #pragma unroll
            for (int r = 0; r < 4; r++)
                Ps[w * 16 + quad * 4 + r][nt * 16 + l15] = f2bf(exp2f(s[nt][r]));

        // O += P V ; l += P @ ones
        #pragma unroll
        for (int ks = 0; ks < 2; ks++) {
            s8v ap = *(const s8v*)&Ps[w * 16 + l15][ks * 32 + quad * 8];
            #pragma unroll
            for (int nt = 0; nt < 4; nt++)
                o_acc[nt] = __builtin_amdgcn_mfma_f32_16x16x32_bf16(ap, bv[nt][ks], o_acc[nt], 0, 0, 0);
            lacc = __builtin_amdgcn_mfma_f32_16x16x32_bf16(ap, ones, lacc, 0, 0, 0);
        }
    }

    // normalize + write ao bf16 [m][1024]
    float inv[4];
    #pragma unroll
    for (int r = 0; r < 4; r++) inv[r] = 1.f / lacc[r];
    #pragma unroll
    for (int nt = 0; nt < 4; nt++)
        #pragma unroll
        for (int r = 0; r < 4; r++) {
            const int row = w * 16 + quad * 4 + r;
            ao[((size_t)b * N_ + q0 + row) * (H_ * DH_) + h * DH_ + nt * 16 + l15] =
                f2bf(o_acc[nt][r] * inv[r]);
        }
}

// ---------------------------------------------------------------------------
// Launch
// ---------------------------------------------------------------------------
extern "C" void kernel_launch(void* const* d_in, const int* in_sizes, int n_in,
                              void* d_out, int out_size, void* d_ws, size_t ws_size,
                              hipStream_t stream) {
    const float* x     = (const float*)d_in[0];   // [B,N,DIM]
    const float* w_qkv = (const float*)d_in[1];   // [3072, 1024]
    const float* w_out = (const float*)d_in[2];   // [1024, 1024]
    const float* b_out = (const float*)d_in[3];   // [1024]
    float* out = (float*)d_out;                   // [B,N,DIM] fp32

    char* ws = (char*)d_ws;
    unsigned short* x_bf    = (unsigned short*)(ws);                        // 16 MB
    unsigned short* wqkv_bf = (unsigned short*)(ws + (((size_t)16) << 20)); //  6 MB
    unsigned short* wout_bf = (unsigned short*)(ws + (((size_t)22) << 20)); //  2 MB
    unsigned short* qkv_bf  = (unsigned short*)(ws + (((size_t)24) << 20)); // 48 MB
    unsigned short* vT      = (unsigned short*)(ws + (((size_t)72) << 20)); // 16 MB
    unsigned short* ao_bf   = (unsigned short*)(ws + (((size_t)88) << 20)); // 16 MB

    const int M = B_ * N_;   // 8192

    // 0) input conversions fp32 -> bf16
    cvt_bf16<<<(M * DIM_) / 1024, 256, 0, stream>>>(x, x_bf, M * DIM_);
    cvt_bf16<<<(E3_ * DIM_) / 1024, 256, 0, stream>>>(w_qkv, wqkv_bf, E3_ * DIM_);
    cvt_bf16<<<(DIM_ * DIM_) / 1024, 256, 0, stream>>>(w_out, wout_bf, DIM_ * DIM_);

    // 1) QKV projection (bf16 MFMA): Q pre-scaled, V redirected to vT
    {
        dim3 grid(E3_ / 128, M / 128);   // (24, 64)
        gemm_mfma<0><<<grid, 256, 0, stream>>>(x_bf, wqkv_bf, nullptr,
                                               qkv_bf, vT, nullptr, M, E3_, DIM_);
    }
    // 2) attention (bf16 MFMA, barrier-free, direct-to-reg fragments)
    {
        dim3 grid(N_ / 64, B_ * H_);     // (32, 64)
        attn_mfma<<<grid, 256, 0, stream>>>(qkv_bf, vT, ao_bf);
    }
    // 3) out projection (bf16 MFMA, fp32 + bias out)
    {
        dim3 grid(DIM_ / 128, M / 128);  // (8, 64)
        gemm_mfma<1><<<grid, 256, 0, stream>>>(ao_bf, wout_bf, b_out,
                                               nullptr, nullptr, out, M, DIM_, DIM_);
    }
    (void)in_sizes; (void)n_in; (void)out_size; (void)ws_size;
}

// Round 7
// 319.949 us; speedup vs baseline: 2.0245x; 2.0245x over previous
//
#include <hip/hip_runtime.h>
#include <hip/hip_bf16.h>
#include <math.h>

// Problem constants
#define B_   4
#define N_   2048
#define DIM_ 1024
#define H_   16
#define DH_  64
#define E3_  3072   // 3*H*DH

typedef __attribute__((ext_vector_type(8))) short  s8v;   // 8 bf16 (4 VGPRs)
typedef __attribute__((ext_vector_type(4))) float  f4v;   // MFMA accumulator

__device__ __forceinline__ unsigned short f2bf(float f) {
    return __builtin_bit_cast(unsigned short, __float2bfloat16(f));
}

// async global->LDS, 16 B per lane; LDS dest = wave-uniform base + lane*16
__device__ __forceinline__ void gload_lds16(const void* g, void* l) {
    __builtin_amdgcn_global_load_lds(
        (const __attribute__((address_space(1))) unsigned int*)(uintptr_t)g,
        (__attribute__((address_space(3))) unsigned int*)(uintptr_t)l,
        16, 0, 0);
}

// ---------------------------------------------------------------------------
// fp32 -> bf16 convert
// ---------------------------------------------------------------------------
__global__ __launch_bounds__(256) void cvt_bf16(
    const float* __restrict__ in, unsigned short* __restrict__ out, int n)
{
    const int i = (blockIdx.x * 256 + threadIdx.x) * 4;
    if (i < n) {
        float4 v = *(const float4*)(in + i);
        *(ushort4*)(out + i) =
            make_ushort4(f2bf(v.x), f2bf(v.y), f2bf(v.z), f2bf(v.w));
    }
}

// ---------------------------------------------------------------------------
// bf16 MFMA GEMM, m97 structure: C[M,Nc] = A[M,K] @ Bw[Nc,K]^T
// 128x128 tile, BK=32, 256 thr = 4 waves (2x2), each wave 64x64 via 4x4
// 16x16x32 MFMAs. global_load_lds width 16, no LDS padding (required).
// MODE 0: out = bf16 qkv; Q-third (cols < 1024) pre-scaled by
//         0.125*log2(e); V-third (cols >= 2048) redirected to
//         vT[b,h,d,n] (packed ushort4 stores along n).
// MODE 1: out = fp32 + bias.
// ---------------------------------------------------------------------------
template<int MODE>
__global__ __launch_bounds__(256) void gemm_mfma(
    const unsigned short* __restrict__ A,
    const unsigned short* __restrict__ Bw,
    const float* __restrict__ bias,
    unsigned short* __restrict__ Cb,   // MODE 0: qkv bf16 [M][Nc]
    unsigned short* __restrict__ Vt,   // MODE 0: [B*H][64][2048]
    float* __restrict__ Cf,            // MODE 1: fp32 [M][Nc]
    int M, int Nc, int K)
{
    __shared__ unsigned short As[128 * 32];
    __shared__ unsigned short Bs[128 * 32];

    const int tid  = threadIdx.x;
    const int w    = tid >> 6;
    const int lane = tid & 63;
    const int quad = lane >> 4;
    const int l15  = lane & 15;
    const int wm   = w & 1, wn = w >> 1;
    const int m0   = blockIdx.y * 128, n0 = blockIdx.x * 128;

    const int srow = lane >> 2;        // 0..15
    const int sch  = (lane & 3) * 8;   // k element offset 0,8,16,24

    f4v acc[4][4];
    #pragma unroll
    for (int i = 0; i < 4; i++)
        #pragma unroll
        for (int j = 0; j < 4; j++) acc[i][j] = (f4v){0.f, 0.f, 0.f, 0.f};

    for (int k0 = 0; k0 < K; k0 += 32) {
        __syncthreads();   // fragment reads of prev iter complete
        #pragma unroll
        for (int i = 0; i < 2; i++) {
            const int rbase = w * 32 + i * 16;   // 16 rows per instruction
            gload_lds16(A  + (size_t)(m0 + rbase + srow) * K + k0 + sch,
                        &As[rbase * 32]);
            gload_lds16(Bw + (size_t)(n0 + rbase + srow) * K + k0 + sch,
                        &Bs[rbase * 32]);
        }
        __syncthreads();   // drains vmcnt -> LDS visible

        s8v af[4], bf[4];
        #pragma unroll
        for (int i = 0; i < 4; i++) {
            af[i] = *(const s8v*)&As[(wm * 64 + i * 16 + l15) * 32 + quad * 8];
            bf[i] = *(const s8v*)&Bs[(wn * 64 + i * 16 + l15) * 32 + quad * 8];
        }
        #pragma unroll
        for (int ms = 0; ms < 4; ms++)
            #pragma unroll
            for (int ns = 0; ns < 4; ns++)
                acc[ms][ns] = __builtin_amdgcn_mfma_f32_16x16x32_bf16(
                    af[ms], bf[ns], acc[ms][ns], 0, 0, 0);
    }

    // epilogue: C/D layout col = l15, row = quad*4 + r
    if (MODE == 0) {
        #pragma unroll
        for (int ns = 0; ns < 4; ns++) {
            const int colb = n0 + wn * 64 + ns * 16;   // wave-uniform
            if (colb < 2048) {
                // fold softmax scale*log2(e) into Q columns
                const float mul = (colb < 1024) ? 0.18033688011112042f : 1.0f;
                #pragma unroll
                for (int ms = 0; ms < 4; ms++)
                    #pragma unroll
                    for (int r = 0; r < 4; r++) {
                        const int row = m0 + wm * 64 + ms * 16 + quad * 4 + r;
                        Cb[(size_t)row * Nc + colb + l15] = f2bf(acc[ms][ns][r] * mul);
                    }
            } else {
                const int e = colb + l15 - 2048;
                const int h = e >> 6, d = e & 63;         // wave-uniform h
                #pragma unroll
                for (int ms = 0; ms < 4; ms++) {
                    const int row = m0 + wm * 64 + ms * 16 + quad * 4; // r=0
                    const int b = row >> 11, n = row & 2047;          // 4-aligned
                    ushort4 pk;
                    pk.x = f2bf(acc[ms][ns][0]); pk.y = f2bf(acc[ms][ns][1]);
                    pk.z = f2bf(acc[ms][ns][2]); pk.w = f2bf(acc[ms][ns][3]);
                    *(ushort4*)&Vt[(((size_t)b * 16 + h) * 64 + d) * 2048 + n] = pk;
                }
            }
        }
    } else {
        #pragma unroll
        for (int ns = 0; ns < 4; ns++) {
            const float bz = bias[n0 + wn * 64 + ns * 16 + l15];
            #pragma unroll
            for (int ms = 0; ms < 4; ms++)
                #pragma unroll
                for (int r = 0; r < 4; r++) {
                    const int row = m0 + wm * 64 + ms * 16 + quad * 4 + r;
                    Cf[(size_t)row * Nc + n0 + wn * 64 + ns * 16 + l15] =
                        acc[ms][ns][r] + bz;
                }
        }
    }
}

// ---------------------------------------------------------------------------
// MFMA flash attention v3: max-free softmax, S^T-swap, 128 q-rows/block.
// - K/V staged in LDS (block-shared, coalesced) — R6 lesson: direct
//   global->VGPR fragment gathers are latency-death (172->476 us).
// - S^T = K Q^T: C-layout gives lane 4 CONTIGUOUS keys of one q-row ->
//   packed ushort4 P-stores (8 ds_write_b64/tile vs 32 ds_write_b16).
// - 4 waves x 32 q-rows: halves per-work LDS fragment traffic + barriers.
// qkv bf16 [m][3072] (Q pre-scaled by 0.125*log2e); vT[b*16+h][d][n] bf16.
// ---------------------------------------------------------------------------
__global__ __launch_bounds__(256) void attn_mfma(
    const unsigned short* __restrict__ qkv,
    const unsigned short* __restrict__ vT,
    unsigned short* __restrict__ ao)
{
    __shared__ __align__(16) unsigned short Ks[64][72];   // [key][d]
    __shared__ __align__(16) unsigned short Vs[64][72];   // [d][key]
    __shared__ __align__(16) unsigned short Ps[128][72];  // [qrow][key]

    const int tid  = threadIdx.x;
    const int w    = tid >> 6;
    const int lane = tid & 63;
    const int quad = lane >> 4;
    const int l15  = lane & 15;

    const int bh = blockIdx.y;
    const int b  = bh >> 4;
    const int h  = bh & 15;
    const int q0 = blockIdx.x * 128;          // 128 q-rows per block

    const unsigned short* qp  = qkv + (size_t)b * N_ * E3_ + (size_t)h * DH_;
    const unsigned short* kp  = qp + 1024;
    const unsigned short* vtp = vT + (size_t)bh * 64 * 2048;

    // Q B-fragments straight from global (one-time): B[n=qrow][k=d]
    s8v bq[2][2];
    #pragma unroll
    for (int mq = 0; mq < 2; mq++) {
        const unsigned short* qrow =
            qp + (size_t)(q0 + w * 32 + mq * 16 + l15) * E3_;
        bq[mq][0] = *(const s8v*)(qrow + quad * 8);
        bq[mq][1] = *(const s8v*)(qrow + 32 + quad * 8);
    }

    // ones B-fragment (bf16 1.0) for row-sum MFMA
    s8v ones;
    #pragma unroll
    for (int i = 0; i < 8; i++) ones[i] = (short)0x3F80;

    f4v o_acc[2][4];   // [mt=q-subtile][ntd=d-subtile]
    #pragma unroll
    for (int mt = 0; mt < 2; mt++)
        #pragma unroll
        for (int nt = 0; nt < 4; nt++) o_acc[mt][nt] = (f4v){0.f, 0.f, 0.f, 0.f};
    f4v lacc[2] = {(f4v){0.f, 0.f, 0.f, 0.f}, (f4v){0.f, 0.f, 0.f, 0.f}};

    for (int kt = 0; kt < N_ / 64; kt++) {
        const int k0 = kt * 64;
        __syncthreads();   // all frag reads of prev iter complete
        #pragma unroll
        for (int p = 0; p < 2; p++) {
            const int f   = tid + p * 256;
            const int row = f >> 3;
            const int c8  = (f & 7) * 8;
            *(s8v*)&Ks[row][c8] = *(const s8v*)(kp + (size_t)(k0 + row) * E3_ + c8);
            *(s8v*)&Vs[row][c8] = *(const s8v*)(vtp + (size_t)row * 2048 + k0 + c8);
        }
        __syncthreads();

        // S^T = K Q^T  (A = K-frag, B = Q-frag); D[m=key][n=qrow]
        f4v st[4][2];
        #pragma unroll
        for (int nt = 0; nt < 4; nt++) {
            const s8v ak0 = *(const s8v*)&Ks[nt * 16 + l15][quad * 8];
            const s8v ak1 = *(const s8v*)&Ks[nt * 16 + l15][32 + quad * 8];
            #pragma unroll
            for (int mq = 0; mq < 2; mq++) {
                st[nt][mq] = (f4v){0.f, 0.f, 0.f, 0.f};
                st[nt][mq] = __builtin_amdgcn_mfma_f32_16x16x32_bf16(ak0, bq[mq][0], st[nt][mq], 0, 0, 0);
                st[nt][mq] = __builtin_amdgcn_mfma_f32_16x16x32_bf16(ak1, bq[mq][1], st[nt][mq], 0, 0, 0);
            }
        }

        // P = exp2(S^T) -> Ps[qrow][key], packed ushort4 (4 contiguous keys)
        #pragma unroll
        for (int nt = 0; nt < 4; nt++)
            #pragma unroll
            for (int mq = 0; mq < 2; mq++) {
                ushort4 pk;
                pk.x = f2bf(exp2f(st[nt][mq][0]));
                pk.y = f2bf(exp2f(st[nt][mq][1]));
                pk.z = f2bf(exp2f(st[nt][mq][2]));
                pk.w = f2bf(exp2f(st[nt][mq][3]));
                *(ushort4*)&Ps[w * 32 + mq * 16 + l15][nt * 16 + quad * 4] = pk;
            }

        // O += P V ; l += P @ ones   (wave-private P rows, no barrier)
        #pragma unroll
        for (int ks = 0; ks < 2; ks++) {
            s8v ap[2];
            #pragma unroll
            for (int mt = 0; mt < 2; mt++) {
                ap[mt] = *(const s8v*)&Ps[w * 32 + mt * 16 + l15][ks * 32 + quad * 8];
                lacc[mt] = __builtin_amdgcn_mfma_f32_16x16x32_bf16(ap[mt], ones, lacc[mt], 0, 0, 0);
            }
            #pragma unroll
            for (int nt = 0; nt < 4; nt++) {
                const s8v bv = *(const s8v*)&Vs[nt * 16 + l15][ks * 32 + quad * 8];
                #pragma unroll
                for (int mt = 0; mt < 2; mt++)
                    o_acc[mt][nt] = __builtin_amdgcn_mfma_f32_16x16x32_bf16(ap[mt], bv, o_acc[mt][nt], 0, 0, 0);
            }
        }
    }

    // normalize + write ao bf16 [m][1024]
    #pragma unroll
    for (int mt = 0; mt < 2; mt++) {
        float inv[4];
        #pragma unroll
        for (int r = 0; r < 4; r++) inv[r] = 1.f / lacc[mt][r];
        #pragma unroll
        for (int nt = 0; nt < 4; nt++)
            #pragma unroll
            for (int r = 0; r < 4; r++) {
                const int row = w * 32 + mt * 16 + quad * 4 + r;
                ao[((size_t)b * N_ + q0 + row) * (H_ * DH_) + h * DH_ + nt * 16 + l15] =
                    f2bf(o_acc[mt][nt][r] * inv[r]);
            }
    }
}

// ---------------------------------------------------------------------------
// Launch
// ---------------------------------------------------------------------------
extern "C" void kernel_launch(void* const* d_in, const int* in_sizes, int n_in,
                              void* d_out, int out_size, void* d_ws, size_t ws_size,
                              hipStream_t stream) {
    const float* x     = (const float*)d_in[0];   // [B,N,DIM]
    const float* w_qkv = (const float*)d_in[1];   // [3072, 1024]
    const float* w_out = (const float*)d_in[2];   // [1024, 1024]
    const float* b_out = (const float*)d_in[3];   // [1024]
    float* out = (float*)d_out;                   // [B,N,DIM] fp32

    char* ws = (char*)d_ws;
    unsigned short* x_bf    = (unsigned short*)(ws);                        // 16 MB
    unsigned short* wqkv_bf = (unsigned short*)(ws + (((size_t)16) << 20)); //  6 MB
    unsigned short* wout_bf = (unsigned short*)(ws + (((size_t)22) << 20)); //  2 MB
    unsigned short* qkv_bf  = (unsigned short*)(ws + (((size_t)24) << 20)); // 48 MB
    unsigned short* vT      = (unsigned short*)(ws + (((size_t)72) << 20)); // 16 MB
    unsigned short* ao_bf   = (unsigned short*)(ws + (((size_t)88) << 20)); // 16 MB

    const int M = B_ * N_;   // 8192

    // 0) input conversions fp32 -> bf16
    cvt_bf16<<<(M * DIM_) / 1024, 256, 0, stream>>>(x, x_bf, M * DIM_);
    cvt_bf16<<<(E3_ * DIM_) / 1024, 256, 0, stream>>>(w_qkv, wqkv_bf, E3_ * DIM_);
    cvt_bf16<<<(DIM_ * DIM_) / 1024, 256, 0, stream>>>(w_out, wout_bf, DIM_ * DIM_);

    // 1) QKV projection (bf16 MFMA): Q pre-scaled, V redirected to vT
    {
        dim3 grid(E3_ / 128, M / 128);   // (24, 64)
        gemm_mfma<0><<<grid, 256, 0, stream>>>(x_bf, wqkv_bf, nullptr,
                                               qkv_bf, vT, nullptr, M, E3_, DIM_);
    }
    // 2) attention (bf16 MFMA, S^T-swap, 128 q-rows/block)
    {
        dim3 grid(N_ / 128, B_ * H_);    // (16, 64) = 1024 blocks = 4/CU
        attn_mfma<<<grid, 256, 0, stream>>>(qkv_bf, vT, ao_bf);
    }
    // 3) out projection (bf16 MFMA, fp32 + bias out)
    {
        dim3 grid(DIM_ / 128, M / 128);  // (8, 64)
        gemm_mfma<1><<<grid, 256, 0, stream>>>(ao_bf, wout_bf, b_out,
                                               nullptr, nullptr, out, M, DIM_, DIM_);
    }
    (void)in_sizes; (void)n_in; (void)out_size; (void)ws_size;
}

// Round 8
// 316.840 us; speedup vs baseline: 2.0444x; 1.0098x over previous
//
#include <hip/hip_runtime.h>
#include <hip/hip_bf16.h>
#include <math.h>

// Problem constants
#define B_   4
#define N_   2048
#define DIM_ 1024
#define H_   16
#define DH_  64
#define E3_  3072   // 3*H*DH

typedef __attribute__((ext_vector_type(8))) short  s8v;   // 8 bf16 (4 VGPRs)
typedef __attribute__((ext_vector_type(4))) float  f4v;   // MFMA accumulator

// fast fp32->bf16: round-half-up (adds 0.5 ulp then truncate). 2 VALU ops.
__device__ __forceinline__ unsigned short f2bf_fast(float f) {
    return (unsigned short)((__builtin_bit_cast(unsigned int, f) + 0x8000u) >> 16);
}
// pack two fp32 -> two bf16 in one u32 via v_perm_b32 (3 VALU ops total)
__device__ __forceinline__ unsigned int pkbf(float a, float b) {
    unsigned int ua = __builtin_bit_cast(unsigned int, a) + 0x8000u;
    unsigned int ub = __builtin_bit_cast(unsigned int, b) + 0x8000u;
    // D bytes: {ub.b3, ub.b2, ua.b3, ua.b2} -> low half = bf16(a), high = bf16(b)
    return __builtin_amdgcn_perm(ub, ua, 0x07060302);
}

// async global->LDS, 16 B per lane; LDS dest = wave-uniform base + lane*16
__device__ __forceinline__ void gload_lds16(const void* g, void* l) {
    __builtin_amdgcn_global_load_lds(
        (const __attribute__((address_space(1))) unsigned int*)(uintptr_t)g,
        (__attribute__((address_space(3))) unsigned int*)(uintptr_t)l,
        16, 0, 0);
}

// ---------------------------------------------------------------------------
// fp32 -> bf16 convert (perm-packed)
// ---------------------------------------------------------------------------
__global__ __launch_bounds__(256) void cvt_bf16(
    const float* __restrict__ in, unsigned short* __restrict__ out, int n)
{
    const int i = (blockIdx.x * 256 + threadIdx.x) * 4;
    if (i < n) {
        float4 v = *(const float4*)(in + i);
        uint2 pk;
        pk.x = pkbf(v.x, v.y);
        pk.y = pkbf(v.z, v.w);
        *(uint2*)(out + i) = pk;
    }
}

// ---------------------------------------------------------------------------
// bf16 MFMA GEMM, m97 structure: C[M,Nc] = A[M,K] @ Bw[Nc,K]^T
// 128x128 tile, BK=32, 256 thr = 4 waves (2x2), each wave 64x64 via 4x4
// 16x16x32 MFMAs. global_load_lds width 16, no LDS padding (required).
// MODE 0: out = bf16 qkv; Q-third pre-scaled by 0.125*log2(e);
//         V-third redirected to vT[b,h,d,n] (uint2-packed stores along n).
// MODE 1: out = fp32 + bias.
// ---------------------------------------------------------------------------
template<int MODE>
__global__ __launch_bounds__(256) void gemm_mfma(
    const unsigned short* __restrict__ A,
    const unsigned short* __restrict__ Bw,
    const float* __restrict__ bias,
    unsigned short* __restrict__ Cb,   // MODE 0: qkv bf16 [M][Nc]
    unsigned short* __restrict__ Vt,   // MODE 0: [B*H][64][2048]
    float* __restrict__ Cf,            // MODE 1: fp32 [M][Nc]
    int M, int Nc, int K)
{
    __shared__ unsigned short As[128 * 32];
    __shared__ unsigned short Bs[128 * 32];

    const int tid  = threadIdx.x;
    const int w    = tid >> 6;
    const int lane = tid & 63;
    const int quad = lane >> 4;
    const int l15  = lane & 15;
    const int wm   = w & 1, wn = w >> 1;
    const int m0   = blockIdx.y * 128, n0 = blockIdx.x * 128;

    const int srow = lane >> 2;        // 0..15
    const int sch  = (lane & 3) * 8;   // k element offset 0,8,16,24

    f4v acc[4][4];
    #pragma unroll
    for (int i = 0; i < 4; i++)
        #pragma unroll
        for (int j = 0; j < 4; j++) acc[i][j] = (f4v){0.f, 0.f, 0.f, 0.f};

    for (int k0 = 0; k0 < K; k0 += 32) {
        __syncthreads();   // fragment reads of prev iter complete
        #pragma unroll
        for (int i = 0; i < 2; i++) {
            const int rbase = w * 32 + i * 16;   // 16 rows per instruction
            gload_lds16(A  + (size_t)(m0 + rbase + srow) * K + k0 + sch,
                        &As[rbase * 32]);
            gload_lds16(Bw + (size_t)(n0 + rbase + srow) * K + k0 + sch,
                        &Bs[rbase * 32]);
        }
        __syncthreads();   // drains vmcnt -> LDS visible

        s8v af[4], bf[4];
        #pragma unroll
        for (int i = 0; i < 4; i++) {
            af[i] = *(const s8v*)&As[(wm * 64 + i * 16 + l15) * 32 + quad * 8];
            bf[i] = *(const s8v*)&Bs[(wn * 64 + i * 16 + l15) * 32 + quad * 8];
        }
        #pragma unroll
        for (int ms = 0; ms < 4; ms++)
            #pragma unroll
            for (int ns = 0; ns < 4; ns++)
                acc[ms][ns] = __builtin_amdgcn_mfma_f32_16x16x32_bf16(
                    af[ms], bf[ns], acc[ms][ns], 0, 0, 0);
    }

    // epilogue: C/D layout col = l15, row = quad*4 + r
    if (MODE == 0) {
        #pragma unroll
        for (int ns = 0; ns < 4; ns++) {
            const int colb = n0 + wn * 64 + ns * 16;   // wave-uniform
            if (colb < 2048) {
                // fold softmax scale*log2(e) into Q columns
                const float mul = (colb < 1024) ? 0.18033688011112042f : 1.0f;
                #pragma unroll
                for (int ms = 0; ms < 4; ms++)
                    #pragma unroll
                    for (int r = 0; r < 4; r++) {
                        const int row = m0 + wm * 64 + ms * 16 + quad * 4 + r;
                        Cb[(size_t)row * Nc + colb + l15] = f2bf_fast(acc[ms][ns][r] * mul);
                    }
            } else {
                const int e = colb + l15 - 2048;
                const int h = e >> 6, d = e & 63;         // wave-uniform h
                #pragma unroll
                for (int ms = 0; ms < 4; ms++) {
                    const int row = m0 + wm * 64 + ms * 16 + quad * 4; // r=0
                    const int b = row >> 11, n = row & 2047;          // 4-aligned
                    uint2 pk;
                    pk.x = pkbf(acc[ms][ns][0], acc[ms][ns][1]);
                    pk.y = pkbf(acc[ms][ns][2], acc[ms][ns][3]);
                    *(uint2*)&Vt[(((size_t)b * 16 + h) * 64 + d) * 2048 + n] = pk;
                }
            }
        }
    } else {
        #pragma unroll
        for (int ns = 0; ns < 4; ns++) {
            const float bz = bias[n0 + wn * 64 + ns * 16 + l15];
            #pragma unroll
            for (int ms = 0; ms < 4; ms++)
                #pragma unroll
                for (int r = 0; r < 4; r++) {
                    const int row = m0 + wm * 64 + ms * 16 + quad * 4 + r;
                    Cf[(size_t)row * Nc + n0 + wn * 64 + ns * 16 + l15] =
                        acc[ms][ns][r] + bz;
                }
        }
    }
}

// ---------------------------------------------------------------------------
// MFMA flash attention v4: max-free softmax, S^T-swap, 2 waves x 64 q-rows.
// - 64 q-rows/wave halves K/V LDS fragment traffic per unit work (R7 was
//   LDS-pipe-bound: ~340 LDS cyc vs 165 MFMA cyc per 32q-unit).
// - perm-packed bf16 (pkbf) for the P-store: 3 ops per fp32 pair vs ~10.
// - 2-wave blocks: barriers only sync 2 waves; 4 blocks/CU (36 KB LDS).
// qkv bf16 [m][3072] (Q pre-scaled by 0.125*log2e); vT[b*16+h][d][n] bf16.
// ---------------------------------------------------------------------------
__global__ __launch_bounds__(128, 2) void attn_mfma(
    const unsigned short* __restrict__ qkv,
    const unsigned short* __restrict__ vT,
    unsigned short* __restrict__ ao)
{
    __shared__ __align__(16) unsigned short Ks[64][72];   // [key][d]
    __shared__ __align__(16) unsigned short Vs[64][72];   // [d][key]
    __shared__ __align__(16) unsigned short Ps[128][72];  // [qrow][key]

    const int tid  = threadIdx.x;
    const int w    = tid >> 6;          // 0..1
    const int lane = tid & 63;
    const int quad = lane >> 4;
    const int l15  = lane & 15;

    const int bh = blockIdx.y;
    const int b  = bh >> 4;
    const int h  = bh & 15;
    const int q0 = blockIdx.x * 128;    // 128 q-rows per block

    const unsigned short* qp  = qkv + (size_t)b * N_ * E3_ + (size_t)h * DH_;
    const unsigned short* kp  = qp + 1024;
    const unsigned short* vtp = vT + (size_t)bh * 64 * 2048;

    // Q B-fragments straight from global (one-time): B[n=qrow][k=d]
    s8v bq[4][2];
    #pragma unroll
    for (int mt = 0; mt < 4; mt++) {
        const unsigned short* qrow =
            qp + (size_t)(q0 + w * 64 + mt * 16 + l15) * E3_;
        bq[mt][0] = *(const s8v*)(qrow + quad * 8);
        bq[mt][1] = *(const s8v*)(qrow + 32 + quad * 8);
    }

    // ones B-fragment (bf16 1.0) for row-sum MFMA
    s8v ones;
    #pragma unroll
    for (int i = 0; i < 8; i++) ones[i] = (short)0x3F80;

    f4v o_acc[4][4];   // [mt=q-subtile][nt=d-subtile]
    #pragma unroll
    for (int mt = 0; mt < 4; mt++)
        #pragma unroll
        for (int nt = 0; nt < 4; nt++) o_acc[mt][nt] = (f4v){0.f, 0.f, 0.f, 0.f};
    f4v lacc[4];
    #pragma unroll
    for (int mt = 0; mt < 4; mt++) lacc[mt] = (f4v){0.f, 0.f, 0.f, 0.f};

    for (int kt = 0; kt < N_ / 64; kt++) {
        const int k0 = kt * 64;
        __syncthreads();   // all frag reads of prev iter complete (2 waves)
        #pragma unroll
        for (int p = 0; p < 4; p++) {
            const int f   = tid + p * 128;     // 0..511
            const int row = f >> 3;
            const int c8  = (f & 7) * 8;
            *(s8v*)&Ks[row][c8] = *(const s8v*)(kp + (size_t)(k0 + row) * E3_ + c8);
            *(s8v*)&Vs[row][c8] = *(const s8v*)(vtp + (size_t)row * 2048 + k0 + c8);
        }
        __syncthreads();

        // S^T = K Q^T  (A = K-frag, B = Q-frag); D[m=key][n=qrow]
        f4v st[4][4];
        #pragma unroll
        for (int nt = 0; nt < 4; nt++) {
            const s8v ak0 = *(const s8v*)&Ks[nt * 16 + l15][quad * 8];
            const s8v ak1 = *(const s8v*)&Ks[nt * 16 + l15][32 + quad * 8];
            #pragma unroll
            for (int mt = 0; mt < 4; mt++) {
                st[nt][mt] = (f4v){0.f, 0.f, 0.f, 0.f};
                st[nt][mt] = __builtin_amdgcn_mfma_f32_16x16x32_bf16(ak0, bq[mt][0], st[nt][mt], 0, 0, 0);
                st[nt][mt] = __builtin_amdgcn_mfma_f32_16x16x32_bf16(ak1, bq[mt][1], st[nt][mt], 0, 0, 0);
            }
        }

        // P = exp2(S^T) -> Ps[qrow][key], perm-packed uint2 (4 contiguous keys)
        #pragma unroll
        for (int nt = 0; nt < 4; nt++)
            #pragma unroll
            for (int mt = 0; mt < 4; mt++) {
                uint2 pk;
                pk.x = pkbf(exp2f(st[nt][mt][0]), exp2f(st[nt][mt][1]));
                pk.y = pkbf(exp2f(st[nt][mt][2]), exp2f(st[nt][mt][3]));
                *(uint2*)&Ps[w * 64 + mt * 16 + l15][nt * 16 + quad * 4] = pk;
            }

        // O += P V ; l += P @ ones   (wave-private P rows, no barrier)
        #pragma unroll
        for (int ks = 0; ks < 2; ks++) {
            s8v ap[4];
            #pragma unroll
            for (int mt = 0; mt < 4; mt++) {
                ap[mt] = *(const s8v*)&Ps[w * 64 + mt * 16 + l15][ks * 32 + quad * 8];
                lacc[mt] = __builtin_amdgcn_mfma_f32_16x16x32_bf16(ap[mt], ones, lacc[mt], 0, 0, 0);
            }
            #pragma unroll
            for (int nt = 0; nt < 4; nt++) {
                const s8v bv = *(const s8v*)&Vs[nt * 16 + l15][ks * 32 + quad * 8];
                #pragma unroll
                for (int mt = 0; mt < 4; mt++)
                    o_acc[mt][nt] = __builtin_amdgcn_mfma_f32_16x16x32_bf16(ap[mt], bv, o_acc[mt][nt], 0, 0, 0);
            }
        }
    }

    // normalize + write ao bf16 [m][1024]
    #pragma unroll
    for (int mt = 0; mt < 4; mt++) {
        float inv[4];
        #pragma unroll
        for (int r = 0; r < 4; r++) inv[r] = 1.f / lacc[mt][r];
        #pragma unroll
        for (int nt = 0; nt < 4; nt++)
            #pragma unroll
            for (int r = 0; r < 4; r++) {
                const int row = w * 64 + mt * 16 + quad * 4 + r;
                ao[((size_t)b * N_ + q0 + row) * (H_ * DH_) + h * DH_ + nt * 16 + l15] =
                    f2bf_fast(o_acc[mt][nt][r] * inv[r]);
            }
    }
}

// ---------------------------------------------------------------------------
// Launch
// ---------------------------------------------------------------------------
extern "C" void kernel_launch(void* const* d_in, const int* in_sizes, int n_in,
                              void* d_out, int out_size, void* d_ws, size_t ws_size,
                              hipStream_t stream) {
    const float* x     = (const float*)d_in[0];   // [B,N,DIM]
    const float* w_qkv = (const float*)d_in[1];   // [3072, 1024]
    const float* w_out = (const float*)d_in[2];   // [1024, 1024]
    const float* b_out = (const float*)d_in[3];   // [1024]
    float* out = (float*)d_out;                   // [B,N,DIM] fp32

    char* ws = (char*)d_ws;
    unsigned short* x_bf    = (unsigned short*)(ws);                        // 16 MB
    unsigned short* wqkv_bf = (unsigned short*)(ws + (((size_t)16) << 20)); //  6 MB
    unsigned short* wout_bf = (unsigned short*)(ws + (((size_t)22) << 20)); //  2 MB
    unsigned short* qkv_bf  = (unsigned short*)(ws + (((size_t)24) << 20)); // 48 MB
    unsigned short* vT      = (unsigned short*)(ws + (((size_t)72) << 20)); // 16 MB
    unsigned short* ao_bf   = (unsigned short*)(ws + (((size_t)88) << 20)); // 16 MB

    const int M = B_ * N_;   // 8192

    // 0) input conversions fp32 -> bf16
    cvt_bf16<<<(M * DIM_) / 1024, 256, 0, stream>>>(x, x_bf, M * DIM_);
    cvt_bf16<<<(E3_ * DIM_) / 1024, 256, 0, stream>>>(w_qkv, wqkv_bf, E3_ * DIM_);
    cvt_bf16<<<(DIM_ * DIM_) / 1024, 256, 0, stream>>>(w_out, wout_bf, DIM_ * DIM_);

    // 1) QKV projection (bf16 MFMA): Q pre-scaled, V redirected to vT
    {
        dim3 grid(E3_ / 128, M / 128);   // (24, 64)
        gemm_mfma<0><<<grid, 256, 0, stream>>>(x_bf, wqkv_bf, nullptr,
                                               qkv_bf, vT, nullptr, M, E3_, DIM_);
    }
    // 2) attention (bf16 MFMA, S^T-swap, 2 waves x 64 q-rows)
    {
        dim3 grid(N_ / 128, B_ * H_);    // (16, 64) = 1024 blocks = 4/CU
        attn_mfma<<<grid, 128, 0, stream>>>(qkv_bf, vT, ao_bf);
    }
    // 3) out projection (bf16 MFMA, fp32 + bias out)
    {
        dim3 grid(DIM_ / 128, M / 128);  // (8, 64)
        gemm_mfma<1><<<grid, 256, 0, stream>>>(ao_bf, wout_bf, b_out,
                                               nullptr, nullptr, out, M, DIM_, DIM_);
    }
    (void)in_sizes; (void)n_in; (void)out_size; (void)ws_size;
}

// Round 9
// 284.326 us; speedup vs baseline: 2.2781x; 1.1144x over previous
//
#include <hip/hip_runtime.h>
#include <hip/hip_bf16.h>
#include <math.h>

// Problem constants
#define B_   4
#define N_   2048
#define DIM_ 1024
#define H_   16
#define DH_  64
#define E3_  3072   // 3*H*DH

typedef __attribute__((ext_vector_type(8))) short  s8v;   // 8 bf16 (4 VGPRs)
typedef __attribute__((ext_vector_type(4))) float  f4v;   // MFMA accumulator

// fast fp32->bf16: round-half-up (adds 0.5 ulp then truncate). 2 VALU ops.
__device__ __forceinline__ unsigned short f2bf_fast(float f) {
    return (unsigned short)((__builtin_bit_cast(unsigned int, f) + 0x8000u) >> 16);
}
// pack two fp32 -> two bf16 in one u32 via v_perm_b32 (3 VALU ops total)
__device__ __forceinline__ unsigned int pkbf(float a, float b) {
    unsigned int ua = __builtin_bit_cast(unsigned int, a) + 0x8000u;
    unsigned int ub = __builtin_bit_cast(unsigned int, b) + 0x8000u;
    return __builtin_amdgcn_perm(ub, ua, 0x07060302);
}

// async global->LDS, 16 B per lane; LDS dest = wave-uniform base + lane*16
__device__ __forceinline__ void gload_lds16(const void* g, void* l) {
    __builtin_amdgcn_global_load_lds(
        (const __attribute__((address_space(1))) unsigned int*)(uintptr_t)g,
        (__attribute__((address_space(3))) unsigned int*)(uintptr_t)l,
        16, 0, 0);
}

// ---------------------------------------------------------------------------
// fp32 -> bf16 convert (perm-packed)
// ---------------------------------------------------------------------------
__global__ __launch_bounds__(256) void cvt_bf16(
    const float* __restrict__ in, unsigned short* __restrict__ out, int n)
{
    const int i = (blockIdx.x * 256 + threadIdx.x) * 4;
    if (i < n) {
        float4 v = *(const float4*)(in + i);
        uint2 pk;
        pk.x = pkbf(v.x, v.y);
        pk.y = pkbf(v.z, v.w);
        *(uint2*)(out + i) = pk;
    }
}

// ---------------------------------------------------------------------------
// bf16 MFMA GEMM, m97 structure: C[M,Nc] = A[M,K] @ Bw[Nc,K]^T
// 128x128 tile, BK=32, 256 thr = 4 waves (2x2), each wave 64x64 via 4x4
// 16x16x32 MFMAs. global_load_lds width 16, no LDS padding (required).
// MODE 0: out = bf16 qkv; Q-third pre-scaled by 0.125*log2(e);
//         V-third redirected to vT[b,h,d,n] (uint2-packed stores along n).
// MODE 1: out = fp32 + bias.
// ---------------------------------------------------------------------------
template<int MODE>
__global__ __launch_bounds__(256) void gemm_mfma(
    const unsigned short* __restrict__ A,
    const unsigned short* __restrict__ Bw,
    const float* __restrict__ bias,
    unsigned short* __restrict__ Cb,   // MODE 0: qkv bf16 [M][Nc]
    unsigned short* __restrict__ Vt,   // MODE 0: [B*H][64][2048]
    float* __restrict__ Cf,            // MODE 1: fp32 [M][Nc]
    int M, int Nc, int K)
{
    __shared__ unsigned short As[128 * 32];
    __shared__ unsigned short Bs[128 * 32];

    const int tid  = threadIdx.x;
    const int w    = tid >> 6;
    const int lane = tid & 63;
    const int quad = lane >> 4;
    const int l15  = lane & 15;
    const int wm   = w & 1, wn = w >> 1;
    const int m0   = blockIdx.y * 128, n0 = blockIdx.x * 128;

    const int srow = lane >> 2;        // 0..15
    const int sch  = (lane & 3) * 8;   // k element offset 0,8,16,24

    f4v acc[4][4];
    #pragma unroll
    for (int i = 0; i < 4; i++)
        #pragma unroll
        for (int j = 0; j < 4; j++) acc[i][j] = (f4v){0.f, 0.f, 0.f, 0.f};

    for (int k0 = 0; k0 < K; k0 += 32) {
        __syncthreads();   // fragment reads of prev iter complete
        #pragma unroll
        for (int i = 0; i < 2; i++) {
            const int rbase = w * 32 + i * 16;   // 16 rows per instruction
            gload_lds16(A  + (size_t)(m0 + rbase + srow) * K + k0 + sch,
                        &As[rbase * 32]);
            gload_lds16(Bw + (size_t)(n0 + rbase + srow) * K + k0 + sch,
                        &Bs[rbase * 32]);
        }
        __syncthreads();   // drains vmcnt -> LDS visible

        s8v af[4], bf[4];
        #pragma unroll
        for (int i = 0; i < 4; i++) {
            af[i] = *(const s8v*)&As[(wm * 64 + i * 16 + l15) * 32 + quad * 8];
            bf[i] = *(const s8v*)&Bs[(wn * 64 + i * 16 + l15) * 32 + quad * 8];
        }
        #pragma unroll
        for (int ms = 0; ms < 4; ms++)
            #pragma unroll
            for (int ns = 0; ns < 4; ns++)
                acc[ms][ns] = __builtin_amdgcn_mfma_f32_16x16x32_bf16(
                    af[ms], bf[ns], acc[ms][ns], 0, 0, 0);
    }

    // epilogue: C/D layout col = l15, row = quad*4 + r
    if (MODE == 0) {
        #pragma unroll
        for (int ns = 0; ns < 4; ns++) {
            const int colb = n0 + wn * 64 + ns * 16;   // wave-uniform
            if (colb < 2048) {
                // fold softmax scale*log2(e) into Q columns
                const float mul = (colb < 1024) ? 0.18033688011112042f : 1.0f;
                #pragma unroll
                for (int ms = 0; ms < 4; ms++)
                    #pragma unroll
                    for (int r = 0; r < 4; r++) {
                        const int row = m0 + wm * 64 + ms * 16 + quad * 4 + r;
                        Cb[(size_t)row * Nc + colb + l15] = f2bf_fast(acc[ms][ns][r] * mul);
                    }
            } else {
                const int e = colb + l15 - 2048;
                const int h = e >> 6, d = e & 63;         // wave-uniform h
                #pragma unroll
                for (int ms = 0; ms < 4; ms++) {
                    const int row = m0 + wm * 64 + ms * 16 + quad * 4; // r=0
                    const int b = row >> 11, n = row & 2047;          // 4-aligned
                    uint2 pk;
                    pk.x = pkbf(acc[ms][ns][0], acc[ms][ns][1]);
                    pk.y = pkbf(acc[ms][ns][2], acc[ms][ns][3]);
                    *(uint2*)&Vt[(((size_t)b * 16 + h) * 64 + d) * 2048 + n] = pk;
                }
            }
        }
    } else {
        #pragma unroll
        for (int ns = 0; ns < 4; ns++) {
            const float bz = bias[n0 + wn * 64 + ns * 16 + l15];
            #pragma unroll
            for (int ms = 0; ms < 4; ms++)
                #pragma unroll
                for (int r = 0; r < 4; r++) {
                    const int row = m0 + wm * 64 + ms * 16 + quad * 4 + r;
                    Cf[(size_t)row * Nc + n0 + wn * 64 + ns * 16 + l15] =
                        acc[ms][ns][r] + bz;
                }
        }
    }
}

// ---------------------------------------------------------------------------
// MFMA flash attention v5: max-free softmax, S^T-swap.
// - 4 waves x 64 q-rows = 256 q-rows/block; grid (8,64)=512 blocks=2/CU.
// - K/V LDS DOUBLE-BUFFERED + register prefetch: one barrier per tile,
//   global-load latency overlapped by the whole tile's compute.
//   (LDS 73.7 KB; 2 blocks/CU either way -> dbuf is occupancy-free.)
// - per-nt S^T -> exp2 -> pack -> store keeps live regs low (R8 had
//   st[4][4]=64 regs live + 128-VGPR cap -> accvgpr shuttling, VALU 54%).
// - raw v_exp_f32 via __builtin_amdgcn_exp2f (no libm edge-code).
// qkv bf16 [m][3072] (Q pre-scaled by 0.125*log2e); vT[b*16+h][d][n] bf16.
// ---------------------------------------------------------------------------
__global__ __launch_bounds__(256, 2) void attn_mfma(
    const unsigned short* __restrict__ qkv,
    const unsigned short* __restrict__ vT,
    unsigned short* __restrict__ ao)
{
    __shared__ __align__(16) unsigned short Ks[2][64][72];   // [buf][key][d]
    __shared__ __align__(16) unsigned short Vs[2][64][72];   // [buf][d][key]
    __shared__ __align__(16) unsigned short Ps[256][72];     // [qrow][key]

    const int tid  = threadIdx.x;
    const int w    = tid >> 6;          // 0..3
    const int lane = tid & 63;
    const int quad = lane >> 4;
    const int l15  = lane & 15;

    const int bh = blockIdx.y;
    const int b  = bh >> 4;
    const int h  = bh & 15;
    const int q0 = blockIdx.x * 256;    // 256 q-rows per block

    const unsigned short* qp  = qkv + (size_t)b * N_ * E3_ + (size_t)h * DH_;
    const unsigned short* kp  = qp + 1024;
    const unsigned short* vtp = vT + (size_t)bh * 64 * 2048;

    // staging mapping: 512 chunks of 16B per tile per tensor, 2 per thread
    const int srow0 = tid >> 3;               // rows 0..31
    const int srow1 = (tid + 256) >> 3;       // rows 32..63
    const int sc8   = (tid & 7) * 8;          // element offset in row

    // Q B-fragments straight from global (one-time): B[n=qrow][k=d]
    s8v bq[4][2];
    #pragma unroll
    for (int mt = 0; mt < 4; mt++) {
        const unsigned short* qrow =
            qp + (size_t)(q0 + w * 64 + mt * 16 + l15) * E3_;
        bq[mt][0] = *(const s8v*)(qrow + quad * 8);
        bq[mt][1] = *(const s8v*)(qrow + 32 + quad * 8);
    }

    // ones B-fragment (bf16 1.0) for row-sum MFMA
    s8v ones;
    #pragma unroll
    for (int i = 0; i < 8; i++) ones[i] = (short)0x3F80;

    f4v o_acc[4][4];   // [mt=q-subtile][nt=d-subtile]
    #pragma unroll
    for (int mt = 0; mt < 4; mt++)
        #pragma unroll
        for (int nt = 0; nt < 4; nt++) o_acc[mt][nt] = (f4v){0.f, 0.f, 0.f, 0.f};
    f4v lacc[4];
    #pragma unroll
    for (int mt = 0; mt < 4; mt++) lacc[mt] = (f4v){0.f, 0.f, 0.f, 0.f};

    // ---- prologue: stage tile 0 into buffer 0 ----
    {
        s8v k0a = *(const s8v*)(kp + (size_t)srow0 * E3_ + sc8);
        s8v k1a = *(const s8v*)(kp + (size_t)srow1 * E3_ + sc8);
        s8v v0a = *(const s8v*)(vtp + (size_t)srow0 * 2048 + sc8);
        s8v v1a = *(const s8v*)(vtp + (size_t)srow1 * 2048 + sc8);
        *(s8v*)&Ks[0][srow0][sc8] = k0a;
        *(s8v*)&Ks[0][srow1][sc8] = k1a;
        *(s8v*)&Vs[0][srow0][sc8] = v0a;
        *(s8v*)&Vs[0][srow1][sc8] = v1a;
    }
    __syncthreads();

    for (int kt = 0; kt < N_ / 64; kt++) {
        const int cur = kt & 1;
        const bool pre = (kt + 1 < N_ / 64);

        // ---- issue next tile's global loads (latency hidden by compute) ----
        s8v pk0, pk1, pv0, pv1;
        if (pre) {
            const int kn = (kt + 1) * 64;
            pk0 = *(const s8v*)(kp + (size_t)(kn + srow0) * E3_ + sc8);
            pk1 = *(const s8v*)(kp + (size_t)(kn + srow1) * E3_ + sc8);
            pv0 = *(const s8v*)(vtp + (size_t)srow0 * 2048 + kn + sc8);
            pv1 = *(const s8v*)(vtp + (size_t)srow1 * 2048 + kn + sc8);
        }

        // ---- S^T = K Q^T per nt; exp2+pack+store immediately ----
        #pragma unroll
        for (int nt = 0; nt < 4; nt++) {
            const s8v ak0 = *(const s8v*)&Ks[cur][nt * 16 + l15][quad * 8];
            const s8v ak1 = *(const s8v*)&Ks[cur][nt * 16 + l15][32 + quad * 8];
            f4v stv[4];
            #pragma unroll
            for (int mt = 0; mt < 4; mt++) {
                stv[mt] = (f4v){0.f, 0.f, 0.f, 0.f};
                stv[mt] = __builtin_amdgcn_mfma_f32_16x16x32_bf16(ak0, bq[mt][0], stv[mt], 0, 0, 0);
                stv[mt] = __builtin_amdgcn_mfma_f32_16x16x32_bf16(ak1, bq[mt][1], stv[mt], 0, 0, 0);
            }
            #pragma unroll
            for (int mt = 0; mt < 4; mt++) {
                uint2 pkd;
                pkd.x = pkbf(__builtin_amdgcn_exp2f(stv[mt][0]),
                             __builtin_amdgcn_exp2f(stv[mt][1]));
                pkd.y = pkbf(__builtin_amdgcn_exp2f(stv[mt][2]),
                             __builtin_amdgcn_exp2f(stv[mt][3]));
                *(uint2*)&Ps[w * 64 + mt * 16 + l15][nt * 16 + quad * 4] = pkd;
            }
        }

        // ---- O += P V ; l += P @ ones  (wave-private P rows) ----
        #pragma unroll
        for (int ks = 0; ks < 2; ks++) {
            s8v ap[4];
            #pragma unroll
            for (int mt = 0; mt < 4; mt++) {
                ap[mt] = *(const s8v*)&Ps[w * 64 + mt * 16 + l15][ks * 32 + quad * 8];
                lacc[mt] = __builtin_amdgcn_mfma_f32_16x16x32_bf16(ap[mt], ones, lacc[mt], 0, 0, 0);
            }
            #pragma unroll
            for (int nt = 0; nt < 4; nt++) {
                const s8v bv = *(const s8v*)&Vs[cur][nt * 16 + l15][ks * 32 + quad * 8];
                #pragma unroll
                for (int mt = 0; mt < 4; mt++)
                    o_acc[mt][nt] = __builtin_amdgcn_mfma_f32_16x16x32_bf16(ap[mt], bv, o_acc[mt][nt], 0, 0, 0);
            }
        }

        // ---- write prefetched tile into back buffer; single barrier ----
        if (pre) {
            const int nxt = cur ^ 1;
            *(s8v*)&Ks[nxt][srow0][sc8] = pk0;
            *(s8v*)&Ks[nxt][srow1][sc8] = pk1;
            *(s8v*)&Vs[nxt][srow0][sc8] = pv0;
            *(s8v*)&Vs[nxt][srow1][sc8] = pv1;
        }
        __syncthreads();
    }

    // normalize + write ao bf16 [m][1024]
    #pragma unroll
    for (int mt = 0; mt < 4; mt++) {
        float inv[4];
        #pragma unroll
        for (int r = 0; r < 4; r++) inv[r] = 1.f / lacc[mt][r];
        #pragma unroll
        for (int nt = 0; nt < 4; nt++)
            #pragma unroll
            for (int r = 0; r < 4; r++) {
                const int row = w * 64 + mt * 16 + quad * 4 + r;
                ao[((size_t)b * N_ + q0 + row) * (H_ * DH_) + h * DH_ + nt * 16 + l15] =
                    f2bf_fast(o_acc[mt][nt][r] * inv[r]);
            }
    }
}

// ---------------------------------------------------------------------------
// Launch
// ---------------------------------------------------------------------------
extern "C" void kernel_launch(void* const* d_in, const int* in_sizes, int n_in,
                              void* d_out, int out_size, void* d_ws, size_t ws_size,
                              hipStream_t stream) {
    const float* x     = (const float*)d_in[0];   // [B,N,DIM]
    const float* w_qkv = (const float*)d_in[1];   // [3072, 1024]
    const float* w_out = (const float*)d_in[2];   // [1024, 1024]
    const float* b_out = (const float*)d_in[3];   // [1024]
    float* out = (float*)d_out;                   // [B,N,DIM] fp32

    char* ws = (char*)d_ws;
    unsigned short* x_bf    = (unsigned short*)(ws);                        // 16 MB
    unsigned short* wqkv_bf = (unsigned short*)(ws + (((size_t)16) << 20)); //  6 MB
    unsigned short* wout_bf = (unsigned short*)(ws + (((size_t)22) << 20)); //  2 MB
    unsigned short* qkv_bf  = (unsigned short*)(ws + (((size_t)24) << 20)); // 48 MB
    unsigned short* vT      = (unsigned short*)(ws + (((size_t)72) << 20)); // 16 MB
    unsigned short* ao_bf   = (unsigned short*)(ws + (((size_t)88) << 20)); // 16 MB

    const int M = B_ * N_;   // 8192

    // 0) input conversions fp32 -> bf16
    cvt_bf16<<<(M * DIM_) / 1024, 256, 0, stream>>>(x, x_bf, M * DIM_);
    cvt_bf16<<<(E3_ * DIM_) / 1024, 256, 0, stream>>>(w_qkv, wqkv_bf, E3_ * DIM_);
    cvt_bf16<<<(DIM_ * DIM_) / 1024, 256, 0, stream>>>(w_out, wout_bf, DIM_ * DIM_);

    // 1) QKV projection (bf16 MFMA): Q pre-scaled, V redirected to vT
    {
        dim3 grid(E3_ / 128, M / 128);   // (24, 64)
        gemm_mfma<0><<<grid, 256, 0, stream>>>(x_bf, wqkv_bf, nullptr,
                                               qkv_bf, vT, nullptr, M, E3_, DIM_);
    }
    // 2) attention (bf16 MFMA, S^T-swap, dbuf K/V, 4 waves x 64 q-rows)
    {
        dim3 grid(N_ / 256, B_ * H_);    // (8, 64) = 512 blocks = 2/CU
        attn_mfma<<<grid, 256, 0, stream>>>(qkv_bf, vT, ao_bf);
    }
    // 3) out projection (bf16 MFMA, fp32 + bias out)
    {
        dim3 grid(DIM_ / 128, M / 128);  // (8, 64)
        gemm_mfma<1><<<grid, 256, 0, stream>>>(ao_bf, wout_bf, b_out,
                                               nullptr, nullptr, out, M, DIM_, DIM_);
    }
    (void)in_sizes; (void)n_in; (void)out_size; (void)ws_size;
}